// Round 13
// baseline (24.893 us; speedup 1.0000x reference)
//
#include <hip/hip_runtime.h>
#include <hip/hip_fp16.h>

#define NR 700
#define KK 250
#define HID 32

typedef unsigned int uint32;
typedef _Float16 f16x8 __attribute__((ext_vector_type(8)));
typedef float f32x4 __attribute__((ext_vector_type(4)));
typedef _Float16 hpair __attribute__((ext_vector_type(2)));

#if __has_builtin(__builtin_amdgcn_exp2f)
#define EXP2F(x) __builtin_amdgcn_exp2f(x)
#else
#define EXP2F(x) exp2f(x)
#endif

__device__ __forceinline__ uint32 packh2(float lo, float hi) {
    hpair p; p.x = (_Float16)lo; p.y = (_Float16)hi;
    return __builtin_bit_cast(uint32, p);
}
__device__ __forceinline__ f16x8 u4f16(uint4 u) { return __builtin_bit_cast(f16x8, u); }

__device__ __forceinline__ void compute_weights(
    int wt, int l,
    const float* __restrict__ Wq, const float* __restrict__ bq,
    const float* __restrict__ Wk,
    const float* __restrict__ Wv, const float* __restrict__ bv,
    float (*Msh)[7], float* wsh, float* wvsh, float SC2Q)
{
    const float* wq = Wq + l * 7 * HID;
    const float* wk = Wk + l * 7 * HID;
    if (wt < 49) {
        int c = wt / 7, cp = wt % 7;
        float s = 0.f;
        #pragma unroll 8
        for (int d = 0; d < HID; ++d) s = fmaf(wq[c * HID + d], wk[cp * HID + d], s);
        Msh[c][cp] = s * SC2Q;
    } else if (wt < 56) {
        int cp = wt - 49;
        float s = 0.f;
        #pragma unroll 8
        for (int d = 0; d < HID; ++d) s = fmaf(bq[l * HID + d], wk[cp * HID + d], s);
        wsh[cp] = s * SC2Q;
    } else if (wt < 63) {
        wvsh[wt - 56] = Wv[l * 7 + (wt - 56)];
    } else if (wt == 63) {
        wvsh[7] = bv[l];
    }
}

// 512 threads = 8 waves. MFMA path, K-duplicated frags: every k-group reads the
// SAME 8-fp16 row, so MFMA computes 4x(t.h); the 0.25 compensation is folded
// into Msh/wsh. C layout: col=lane&15 = query i, row=grp*4+rg = j -> softmax
// accumulates lane-locally over j; final reduce = shfl_xor(16), shfl_xor(32).
// Wave w owns i-tiles {2w, 2w+1}; loops over 16 j-tiles with unroll 2.
// __launch_bounds__(512,6): 3 blocks/CU -> all 700 blocks co-resident (no tail).
__global__ __launch_bounds__(512, 6) void mlra_kernel(
    const float* __restrict__ power,
    const int*   __restrict__ ele_idx,
    const int*   __restrict__ azi_idx,
    const float* __restrict__ ele_emb,
    const float* __restrict__ azi_emb,
    const float* __restrict__ Wq,
    const float* __restrict__ bq,
    const float* __restrict__ Wk,
    const float* __restrict__ bk,
    const float* __restrict__ Wv,
    const float* __restrict__ bv,
    float* __restrict__ out)
{
    __shared__ uint4 hh[256];      // h rows fp16: (h0,h1)(h2,h3)(h4,h5)(h6,0); pads zero
    __shared__ uint4 tt[256];      // t rows fp16 (scaled by SC2/4)
    __shared__ float vsh[256];     // v per row fp32; pads 0
    __shared__ float Msh[2][7][7];
    __shared__ float wsh[2][7];
    __shared__ float wvsh[2][8];

    const int r    = blockIdx.x;
    const int tid  = threadIdx.x;
    const int lane = tid & 63;
    const int wid  = tid >> 6;
    const int col  = lane & 15;    // query index within i-tile
    const int grp  = lane >> 4;    // j-row-group in C

    // SCALE * log2(e) * 0.25 (K-duplication compensation)
    const float SC2Q = 0.17677669529663687f * 1.4426950408889634f * 0.25f;

    // ---- prologue: h build (threads 0-255) || both layers' weights (waves 4,5) ----
    if (tid < 256) {
        float hv[7];
        if (tid < KK) {
            int g = r * KK + tid;
            hv[0] = power[g];
            int ei = ele_idx[g];
            int ai = azi_idx[g];
            hv[1] = ele_emb[ei * 3 + 0];
            hv[2] = ele_emb[ei * 3 + 1];
            hv[3] = ele_emb[ei * 3 + 2];
            hv[4] = azi_emb[ai * 3 + 0];
            hv[5] = azi_emb[ai * 3 + 1];
            hv[6] = azi_emb[ai * 3 + 2];
        } else {
            #pragma unroll
            for (int c = 0; c < 7; ++c) hv[c] = 0.f;
        }
        uint4 u;
        u.x = packh2(hv[0], hv[1]);
        u.y = packh2(hv[2], hv[3]);
        u.z = packh2(hv[4], hv[5]);
        u.w = packh2(hv[6], 0.f);
        hh[tid] = u;
        vsh[tid] = 0.f;
    } else if (tid < 384) {
        int l = (tid - 256) >> 6;  // wave 4 -> layer 0, wave 5 -> layer 1
        compute_weights(tid & 63, l, Wq, bq, Wk, Wv, bv, Msh[l], wsh[l], wvsh[l], SC2Q);
    }
    __syncthreads();   // (1) h + both layers' weights ready

    const int n0 = 2 * wid;        // owned i-tiles
    const int n1 = 2 * wid + 1;
    const f32x4 cz = {0.f, 0.f, 0.f, 0.f};

    float x0 = 0.f, x1 = 0.f;

    for (int l = 0; l < 2; ++l) {
        // ---- t-phase: threads 0-255, one row each; writes tt row + vsh ----
        if (tid < 256) {
            uint4 u = hh[tid];
            hpair pa = __builtin_bit_cast(hpair, u.x);
            hpair pb = __builtin_bit_cast(hpair, u.y);
            hpair pc = __builtin_bit_cast(hpair, u.z);
            hpair pd = __builtin_bit_cast(hpair, u.w);
            float hv[7] = {(float)pa.x, (float)pa.y, (float)pb.x, (float)pb.y,
                           (float)pc.x, (float)pc.y, (float)pd.x};
            float tv[7];
            #pragma unroll
            for (int cp = 0; cp < 7; ++cp) {
                float s = wsh[l][cp];
                #pragma unroll
                for (int c = 0; c < 7; ++c) s = fmaf(hv[c], Msh[l][c][cp], s);
                tv[cp] = s;
            }
            float v = wvsh[l][7];
            #pragma unroll
            for (int c = 0; c < 7; ++c) v = fmaf(hv[c], wvsh[l][c], v);
            uint4 t4;
            t4.x = packh2(tv[0], tv[1]);
            t4.y = packh2(tv[2], tv[3]);
            t4.z = packh2(tv[4], tv[5]);
            t4.w = packh2(tv[6], 0.f);
            tt[tid] = t4;
            vsh[tid] = (tid < KK) ? v : 0.f;
        }
        __syncthreads();   // (2) tt + vsh ready

        // ---- B frags: t rows of our 2 i-tiles (K-duplicated, no conditionals) ----
        f16x8 bt0 = u4f16(tt[n0 * 16 + col]);
        f16x8 bt1 = u4f16(tt[n1 * 16 + col]);

        float ss0 = 0.f, oo0 = 0.f, ss1 = 0.f, oo1 = 0.f;
        #pragma unroll 2
        for (int jt = 0; jt < 16; ++jt) {
            f16x8 ah = u4f16(hh[jt * 16 + col]);   // A: j-rows, K-duplicated
            f32x4 vv = *reinterpret_cast<const f32x4*>(&vsh[jt * 16 + grp * 4]);
            f32x4 c0 = __builtin_amdgcn_mfma_f32_16x16x32_f16(ah, bt0, cz, 0, 0, 0);
            f32x4 c1 = __builtin_amdgcn_mfma_f32_16x16x32_f16(ah, bt1, cz, 0, 0, 0);
            #pragma unroll
            for (int rg = 0; rg < 4; ++rg) {
                float p0 = EXP2F(c0[rg]);
                float p1 = EXP2F(c1[rg]);
                float vj = vv[rg];
                ss0 += p0; oo0 = fmaf(p0, vj, oo0);
                ss1 += p1; oo1 = fmaf(p1, vj, oo1);
            }
        }
        // pad j rows 250..255 (jt=15): this lane saw clamp(4*grp-6,0,4) pads (p=1,v=0)
        {
            int ex = 4 * grp - 6;
            ex = ex < 0 ? 0 : (ex > 4 ? 4 : ex);
            float exf = (float)ex;
            ss0 -= exf; ss1 -= exf;
        }

        // ---- reduce across the 4 j-row-groups (lane bits 4,5) ----
        ss0 += __shfl_xor(ss0, 16); ss0 += __shfl_xor(ss0, 32);
        oo0 += __shfl_xor(oo0, 16); oo0 += __shfl_xor(oo0, 32);
        ss1 += __shfl_xor(ss1, 16); ss1 += __shfl_xor(ss1, 32);
        oo1 += __shfl_xor(oo1, 16); oo1 += __shfl_xor(oo1, 32);
        x0 = oo0 / ss0;
        x1 = oo1 / ss1;

        if (l == 0) {
            __syncthreads();   // (3) all MFMA-phase reads of hh done
            if (grp == 0) {
                int i0 = n0 * 16 + col;
                int i1 = n1 * 16 + col;
                reinterpret_cast<_Float16*>(hh)[i0 * 8] = (_Float16)x0;  // i0 <= 239
                if (i1 < KK) reinterpret_cast<_Float16*>(hh)[i1 * 8] = (_Float16)x1;
            }
            __syncthreads();   // (4) x-update published
        }
    }

    if (grp == 0) {
        int i0 = n0 * 16 + col;
        int i1 = n1 * 16 + col;
        out[r * KK + i0] = x0;                    // i0 <= 239 always valid
        if (i1 < KK) out[r * KK + i1] = x1;
    }
}

extern "C" void kernel_launch(void* const* d_in, const int* in_sizes, int n_in,
                              void* d_out, int out_size, void* d_ws, size_t ws_size,
                              hipStream_t stream) {
    const float* power   = (const float*)d_in[0];
    const int*   ele     = (const int*)d_in[1];
    const int*   azi     = (const int*)d_in[2];
    const float* ele_emb = (const float*)d_in[3];
    const float* azi_emb = (const float*)d_in[4];
    const float* Wq      = (const float*)d_in[5];
    const float* bq      = (const float*)d_in[6];
    const float* Wk      = (const float*)d_in[7];
    const float* bk      = (const float*)d_in[8];
    const float* Wv      = (const float*)d_in[9];
    const float* bv      = (const float*)d_in[10];
    float* outp = (float*)d_out;
    (void)bk;

    hipLaunchKernelGGL(mlra_kernel, dim3(NR), dim3(512), 0, stream,
                       power, ele, azi, ele_emb, azi_emb, Wq, bq, Wk, bk, Wv, bv, outp);
}

// Round 14
// 23.319 us; speedup vs baseline: 1.0675x; 1.0675x over previous
//
#include <hip/hip_runtime.h>
#include <hip/hip_fp16.h>

#define NR 700
#define KK 250
#define HID 32

typedef unsigned int uint32;
typedef _Float16 f16x8 __attribute__((ext_vector_type(8)));
typedef float f32x4 __attribute__((ext_vector_type(4)));
typedef _Float16 hpair __attribute__((ext_vector_type(2)));

#if __has_builtin(__builtin_amdgcn_exp2f)
#define EXP2F(x) __builtin_amdgcn_exp2f(x)
#else
#define EXP2F(x) exp2f(x)
#endif

__device__ __forceinline__ uint32 packh2(float lo, float hi) {
    hpair p; p.x = (_Float16)lo; p.y = (_Float16)hi;
    return __builtin_bit_cast(uint32, p);
}
__device__ __forceinline__ f16x8 u4f16(uint4 u) { return __builtin_bit_cast(f16x8, u); }

__device__ __forceinline__ void compute_weights(
    int wt, int l,
    const float* __restrict__ Wq, const float* __restrict__ bq,
    const float* __restrict__ Wk,
    const float* __restrict__ Wv, const float* __restrict__ bv,
    float (*Msh)[7], float* wsh, float* wvsh, float SC2Q)
{
    const float* wq = Wq + l * 7 * HID;
    const float* wk = Wk + l * 7 * HID;
    if (wt < 49) {
        int c = wt / 7, cp = wt % 7;
        float s = 0.f;
        #pragma unroll 8
        for (int d = 0; d < HID; ++d) s = fmaf(wq[c * HID + d], wk[cp * HID + d], s);
        Msh[c][cp] = s * SC2Q;
    } else if (wt < 56) {
        int cp = wt - 49;
        float s = 0.f;
        #pragma unroll 8
        for (int d = 0; d < HID; ++d) s = fmaf(bq[l * HID + d], wk[cp * HID + d], s);
        wsh[cp] = s * SC2Q;
    } else if (wt < 63) {
        wvsh[wt - 56] = Wv[l * 7 + (wt - 56)];
    } else if (wt == 63) {
        wvsh[7] = bv[l];
    }
}

// 256 threads = 4 waves. Each wave owns 4 i-tiles (wid*4..+3); per j-tile one
// ds_read_b128 (h row) feeds 4 MFMAs (K-duplicated frags, 0.25 folded into
// weights). v packed as fp16 so one b128 serves TWO j-tiles. C layout:
// col=lane&15 = i, row=grp*4+rg = j -> lane-local softmax; reduce = 2 shfl_xor.
__global__ __launch_bounds__(256, 4) void mlra_kernel(
    const float* __restrict__ power,
    const int*   __restrict__ ele_idx,
    const int*   __restrict__ azi_idx,
    const float* __restrict__ ele_emb,
    const float* __restrict__ azi_emb,
    const float* __restrict__ Wq,
    const float* __restrict__ bq,
    const float* __restrict__ Wk,
    const float* __restrict__ bk,
    const float* __restrict__ Wv,
    const float* __restrict__ bv,
    float* __restrict__ out)
{
    __shared__ uint4 hh[256];      // h rows fp16: (h0,h1)(h2,h3)(h4,h5)(h6,0); pads zero
    __shared__ uint4 tt[256];      // t rows fp16 (scaled by SC2/4)
    __shared__ uint4 vpk[8][4];    // v fp16: [jtp][grp] = {v[2jtp tile, grp*4+0..3], v[2jtp+1 tile, ...]}
    __shared__ float Msh[2][7][7];
    __shared__ float wsh[2][7];
    __shared__ float wvsh[2][8];

    const int r    = blockIdx.x;
    const int tid  = threadIdx.x;     // 0..255
    const int lane = tid & 63;
    const int wid  = tid >> 6;        // 0..3
    const int col  = lane & 15;       // query index within i-tile
    const int grp  = lane >> 4;       // j-row-group in C

    // SCALE * log2(e) * 0.25 (K-duplication compensation)
    const float SC2Q = 0.17677669529663687f * 1.4426950408889634f * 0.25f;

    // ---- prologue: every thread builds one h row; threads 0-127 also weights ----
    {
        float hv[7];
        if (tid < KK) {
            int g = r * KK + tid;
            hv[0] = power[g];
            int ei = ele_idx[g];
            int ai = azi_idx[g];
            hv[1] = ele_emb[ei * 3 + 0];
            hv[2] = ele_emb[ei * 3 + 1];
            hv[3] = ele_emb[ei * 3 + 2];
            hv[4] = azi_emb[ai * 3 + 0];
            hv[5] = azi_emb[ai * 3 + 1];
            hv[6] = azi_emb[ai * 3 + 2];
        } else {
            #pragma unroll
            for (int c = 0; c < 7; ++c) hv[c] = 0.f;
        }
        uint4 u;
        u.x = packh2(hv[0], hv[1]);
        u.y = packh2(hv[2], hv[3]);
        u.z = packh2(hv[4], hv[5]);
        u.w = packh2(hv[6], 0.f);
        hh[tid] = u;
    }
    if (tid < 128) {
        compute_weights(tid & 63, tid >> 6, Wq, bq, Wk, Wv, bv,
                        Msh[tid >> 6], wsh[tid >> 6], wvsh[tid >> 6], SC2Q);
    }
    __syncthreads();   // (1) h + both layers' weights ready

    const f32x4 cz = {0.f, 0.f, 0.f, 0.f};
    float x0 = 0.f, x1 = 0.f, x2 = 0.f, x3 = 0.f;

    for (int l = 0; l < 2; ++l) {
        // ---- t-phase: all 256 threads, one row each; writes tt + packed v ----
        {
            uint4 u = hh[tid];
            hpair pa = __builtin_bit_cast(hpair, u.x);
            hpair pb = __builtin_bit_cast(hpair, u.y);
            hpair pc = __builtin_bit_cast(hpair, u.z);
            hpair pd = __builtin_bit_cast(hpair, u.w);
            float hv[7] = {(float)pa.x, (float)pa.y, (float)pb.x, (float)pb.y,
                           (float)pc.x, (float)pc.y, (float)pd.x};
            float tv[7];
            #pragma unroll
            for (int cp = 0; cp < 7; ++cp) {
                float s = wsh[l][cp];
                #pragma unroll
                for (int c = 0; c < 7; ++c) s = fmaf(hv[c], Msh[l][c][cp], s);
                tv[cp] = s;
            }
            float v = wvsh[l][7];
            #pragma unroll
            for (int c = 0; c < 7; ++c) v = fmaf(hv[c], wvsh[l][c], v);
            uint4 t4;
            t4.x = packh2(tv[0], tv[1]);
            t4.y = packh2(tv[2], tv[3]);
            t4.z = packh2(tv[4], tv[5]);
            t4.w = packh2(tv[6], 0.f);
            tt[tid] = t4;
            // packed v slot: (jtp*4 + grp_row)*8 + halfsel*4 + rg
            int jtp = tid >> 5, halfsel = (tid >> 4) & 1, grow = (tid >> 2) & 3, rg = tid & 3;
            reinterpret_cast<_Float16*>(vpk)[(jtp * 4 + grow) * 8 + halfsel * 4 + rg] =
                (_Float16)((tid < KK) ? v : 0.f);
        }
        __syncthreads();   // (2) tt + v ready

        // ---- B frags: 4 owned i-tiles (K-duplicated) ----
        f16x8 bt0 = u4f16(tt[(wid * 4 + 0) * 16 + col]);
        f16x8 bt1 = u4f16(tt[(wid * 4 + 1) * 16 + col]);
        f16x8 bt2 = u4f16(tt[(wid * 4 + 2) * 16 + col]);
        f16x8 bt3 = u4f16(tt[(wid * 4 + 3) * 16 + col]);

        float ss0 = 0.f, oo0 = 0.f, ss1 = 0.f, oo1 = 0.f;
        float ss2 = 0.f, oo2 = 0.f, ss3 = 0.f, oo3 = 0.f;
        #pragma unroll 1
        for (int jtp = 0; jtp < 8; ++jtp) {
            f16x8 ahe = u4f16(hh[jtp * 32 + col]);        // even j-tile rows
            f16x8 aho = u4f16(hh[jtp * 32 + 16 + col]);   // odd j-tile rows
            uint4 vq  = vpk[jtp][grp];
            hpair v01e = __builtin_bit_cast(hpair, vq.x);
            hpair v23e = __builtin_bit_cast(hpair, vq.y);
            hpair v01o = __builtin_bit_cast(hpair, vq.z);
            hpair v23o = __builtin_bit_cast(hpair, vq.w);
            float ve0 = (float)v01e.x, ve1 = (float)v01e.y;
            float ve2 = (float)v23e.x, ve3 = (float)v23e.y;
            float vo0 = (float)v01o.x, vo1 = (float)v01o.y;
            float vo2 = (float)v23o.x, vo3 = (float)v23o.y;

            f32x4 ce0 = __builtin_amdgcn_mfma_f32_16x16x32_f16(ahe, bt0, cz, 0, 0, 0);
            f32x4 ce1 = __builtin_amdgcn_mfma_f32_16x16x32_f16(ahe, bt1, cz, 0, 0, 0);
            f32x4 ce2 = __builtin_amdgcn_mfma_f32_16x16x32_f16(ahe, bt2, cz, 0, 0, 0);
            f32x4 ce3 = __builtin_amdgcn_mfma_f32_16x16x32_f16(ahe, bt3, cz, 0, 0, 0);
            f32x4 co0 = __builtin_amdgcn_mfma_f32_16x16x32_f16(aho, bt0, cz, 0, 0, 0);
            f32x4 co1 = __builtin_amdgcn_mfma_f32_16x16x32_f16(aho, bt1, cz, 0, 0, 0);
            f32x4 co2 = __builtin_amdgcn_mfma_f32_16x16x32_f16(aho, bt2, cz, 0, 0, 0);
            f32x4 co3 = __builtin_amdgcn_mfma_f32_16x16x32_f16(aho, bt3, cz, 0, 0, 0);

            #define ACC(ct, vv0, vv1, vv2, vv3, SS, OO)                         \
            {                                                                    \
                float p0 = EXP2F(ct[0]); float p1 = EXP2F(ct[1]);                \
                float p2 = EXP2F(ct[2]); float p3 = EXP2F(ct[3]);                \
                SS += (p0 + p1) + (p2 + p3);                                     \
                OO = fmaf(p0, vv0, OO); OO = fmaf(p1, vv1, OO);                  \
                OO = fmaf(p2, vv2, OO); OO = fmaf(p3, vv3, OO);                  \
            }
            ACC(ce0, ve0, ve1, ve2, ve3, ss0, oo0)
            ACC(ce1, ve0, ve1, ve2, ve3, ss1, oo1)
            ACC(ce2, ve0, ve1, ve2, ve3, ss2, oo2)
            ACC(ce3, ve0, ve1, ve2, ve3, ss3, oo3)
            ACC(co0, vo0, vo1, vo2, vo3, ss0, oo0)
            ACC(co1, vo0, vo1, vo2, vo3, ss1, oo1)
            ACC(co2, vo0, vo1, vo2, vo3, ss2, oo2)
            ACC(co3, vo0, vo1, vo2, vo3, ss3, oo3)
            #undef ACC
        }
        // pad j rows 250..255 (odd tile of jtp=7): clamp(4*grp-6,0,4) pads (p=1,v=0)
        {
            int ex = 4 * grp - 6;
            ex = ex < 0 ? 0 : (ex > 4 ? 4 : ex);
            float exf = (float)ex;
            ss0 -= exf; ss1 -= exf; ss2 -= exf; ss3 -= exf;
        }

        // ---- reduce across the 4 j-row-groups (lane bits 4,5) ----
        ss0 += __shfl_xor(ss0, 16); ss0 += __shfl_xor(ss0, 32);
        oo0 += __shfl_xor(oo0, 16); oo0 += __shfl_xor(oo0, 32);
        ss1 += __shfl_xor(ss1, 16); ss1 += __shfl_xor(ss1, 32);
        oo1 += __shfl_xor(oo1, 16); oo1 += __shfl_xor(oo1, 32);
        ss2 += __shfl_xor(ss2, 16); ss2 += __shfl_xor(ss2, 32);
        oo2 += __shfl_xor(oo2, 16); oo2 += __shfl_xor(oo2, 32);
        ss3 += __shfl_xor(ss3, 16); ss3 += __shfl_xor(ss3, 32);
        oo3 += __shfl_xor(oo3, 16); oo3 += __shfl_xor(oo3, 32);
        x0 = oo0 / ss0; x1 = oo1 / ss1; x2 = oo2 / ss2; x3 = oo3 / ss3;

        if (l == 0) {
            __syncthreads();   // (3) all MFMA-phase reads of hh done
            if (grp == 0) {
                int i0 = (wid * 4 + 0) * 16 + col;
                int i1 = (wid * 4 + 1) * 16 + col;
                int i2 = (wid * 4 + 2) * 16 + col;
                int i3 = (wid * 4 + 3) * 16 + col;
                _Float16* hhf = reinterpret_cast<_Float16*>(hh);
                hhf[i0 * 8] = (_Float16)x0;
                hhf[i1 * 8] = (_Float16)x1;
                hhf[i2 * 8] = (_Float16)x2;
                if (i3 < KK) hhf[i3 * 8] = (_Float16)x3;
            }
            __syncthreads();   // (4) x-update published
        }
    }

    if (grp == 0) {
        int i0 = (wid * 4 + 0) * 16 + col;
        int i1 = (wid * 4 + 1) * 16 + col;
        int i2 = (wid * 4 + 2) * 16 + col;
        int i3 = (wid * 4 + 3) * 16 + col;
        out[r * KK + i0] = x0;
        out[r * KK + i1] = x1;
        out[r * KK + i2] = x2;
        if (i3 < KK) out[r * KK + i3] = x3;
    }
}

extern "C" void kernel_launch(void* const* d_in, const int* in_sizes, int n_in,
                              void* d_out, int out_size, void* d_ws, size_t ws_size,
                              hipStream_t stream) {
    const float* power   = (const float*)d_in[0];
    const int*   ele     = (const int*)d_in[1];
    const int*   azi     = (const int*)d_in[2];
    const float* ele_emb = (const float*)d_in[3];
    const float* azi_emb = (const float*)d_in[4];
    const float* Wq      = (const float*)d_in[5];
    const float* bq      = (const float*)d_in[6];
    const float* Wk      = (const float*)d_in[7];
    const float* bk      = (const float*)d_in[8];
    const float* Wv      = (const float*)d_in[9];
    const float* bv      = (const float*)d_in[10];
    float* outp = (float*)d_out;
    (void)bk;

    hipLaunchKernelGGL(mlra_kernel, dim3(NR), dim3(256), 0, stream,
                       power, ele, azi, ele_emb, azi_emb, Wq, bq, Wk, bk, Wv, bv, outp);
}